// Round 1
// baseline (153.098 us; speedup 1.0000x reference)
//
#include <hip/hip_runtime.h>
#include <hip/hip_bf16.h>

// pRotatE scoring: out[b,e] = -sum_d sin(ph[b,d] - pe[e,d])
//   ph[b,d] = head[b,d]*PI/max_ent + rel[b,d]*PI/max_rel
//   pe[e,d] = ent[e,d]*PI/max_ent
// Rewritten via sin(x-y)=sinx cosy - cosx siny as a bf16 MFMA GEMM:
//   out = A(64x512) * B(512x50000),  A[b][2d]=cos(ph), A[b][2d+1]=-sin(ph)
//                                    B[2d][e]=sin(pe), B[2d+1][e]=cos(pe)
// v_sin_f32/v_cos_f32 take REVOLUTIONS: rev = x * (0.5/max)  (|rev|<=1, no
// range reduction needed).

typedef __bf16 bf16x8 __attribute__((ext_vector_type(8)));
typedef float f32x4 __attribute__((ext_vector_type(4)));

#define EMB_D 256   // emb_dim
#define KDIM 512    // 2 * EMB_D
#define BATCH 64

__global__ void init_ws_kernel(unsigned int* ws) {
  ws[0] = 0u;
  ws[1] = 0u;
}

// blocks [0, grid/2) reduce ent, [grid/2, grid) reduce rel
__global__ __launch_bounds__(256) void absmax_kernel(
    const float* __restrict__ ent, const float* __restrict__ rel,
    int n_ent, int n_rel, unsigned int* __restrict__ ws) {
  const int half = gridDim.x >> 1;
  const bool is_ent = (int)blockIdx.x < half;
  const float* __restrict__ src = is_ent ? ent : rel;
  const int n = is_ent ? n_ent : n_rel;
  unsigned int* dst = is_ent ? (ws + 0) : (ws + 1);
  const int bid = is_ent ? blockIdx.x : blockIdx.x - half;
  const int nvec = n >> 2;  // n divisible by 4 (50000*256)
  const int stride = half * blockDim.x;
  const float4* __restrict__ v = (const float4*)src;
  float m = 0.0f;
  for (int i = bid * blockDim.x + threadIdx.x; i < nvec; i += stride) {
    float4 x = v[i];
    m = fmaxf(m, fabsf(x.x));
    m = fmaxf(m, fabsf(x.y));
    m = fmaxf(m, fabsf(x.z));
    m = fmaxf(m, fabsf(x.w));
  }
#pragma unroll
  for (int off = 32; off > 0; off >>= 1)
    m = fmaxf(m, __shfl_down(m, off, 64));
  if ((threadIdx.x & 63) == 0) atomicMax(dst, __float_as_uint(m));
}

// A[64][512] bf16, stored as uint pairs: uint index b*256+d holds
// (low) A[b][2d] = cos(ph), (high) A[b][2d+1] = -sin(ph)
__global__ __launch_bounds__(256) void build_A_kernel(
    const int* __restrict__ triples, const float* __restrict__ ent,
    const float* __restrict__ rel, const unsigned int* __restrict__ ws,
    unsigned int* __restrict__ A) {
  const int b = blockIdx.x;    // 0..63
  const int d = threadIdx.x;   // 0..255
  const float max_e = __uint_as_float(ws[0]);
  const float max_r = __uint_as_float(ws[1]);
  const int h = triples[b * 3 + 0];
  const int r = triples[b * 3 + 1];
  // phase in revolutions: phase_rad/(2*pi) = x/(2*max)
  const float rev = ent[h * EMB_D + d] * (0.5f / max_e) +
                    rel[r * EMB_D + d] * (0.5f / max_r);
  const float s = __builtin_amdgcn_sinf(rev);
  const float c = __builtin_amdgcn_cosf(rev);
  const unsigned int cb = (unsigned int)__bfloat16_as_ushort(__float2bfloat16(c));
  const unsigned int nsb = (unsigned int)__bfloat16_as_ushort(__float2bfloat16(-s));
  A[b * (KDIM / 2) + d] = cb | (nsb << 16);
}

// One wave per block; wave computes C[64 b][16 e] = sum over K=512.
// 4 m-tiles of mfma_f32_16x16x32_bf16, 16 k-steps.
// B fragment built in-register: float4 ent load -> scale -> v_sin/v_cos -> bf16.
__global__ __launch_bounds__(64) void score_kernel(
    const float* __restrict__ ent, const unsigned int* __restrict__ A,
    const unsigned int* __restrict__ ws, float* __restrict__ out, int NE) {
  const int lane = threadIdx.x;
  const int lo = lane & 15;
  const int hi = lane >> 4;
  const int e = blockIdx.x * 16 + lo;
  const float scale = 0.5f / __uint_as_float(ws[0]);  // ent revolutions scale

  f32x4 acc0 = {0.f, 0.f, 0.f, 0.f};
  f32x4 acc1 = {0.f, 0.f, 0.f, 0.f};
  f32x4 acc2 = {0.f, 0.f, 0.f, 0.f};
  f32x4 acc3 = {0.f, 0.f, 0.f, 0.f};

  const float4* __restrict__ erow = (const float4*)(ent + (long)e * EMB_D);

  union UA {
    uint4 u;
    bf16x8 v;
  };

  // software pipeline the ent load one step ahead
  float4 pe = erow[hi];
#pragma unroll 1
  for (int ks = 0; ks < 16; ++ks) {
    float4 pe_next = (ks < 15) ? erow[(ks + 1) * 4 + hi] : pe;

    // build B fragment: elem 2t = sin(pe[dbase+t]), 2t+1 = cos(pe[dbase+t])
    unsigned int bw[4];
    {
      float f0 = pe.x * scale, f1 = pe.y * scale, f2 = pe.z * scale,
            f3 = pe.w * scale;
      float s0 = __builtin_amdgcn_sinf(f0), c0 = __builtin_amdgcn_cosf(f0);
      float s1 = __builtin_amdgcn_sinf(f1), c1 = __builtin_amdgcn_cosf(f1);
      float s2 = __builtin_amdgcn_sinf(f2), c2 = __builtin_amdgcn_cosf(f2);
      float s3 = __builtin_amdgcn_sinf(f3), c3 = __builtin_amdgcn_cosf(f3);
      bw[0] = (unsigned int)__bfloat16_as_ushort(__float2bfloat16(s0)) |
              ((unsigned int)__bfloat16_as_ushort(__float2bfloat16(c0)) << 16);
      bw[1] = (unsigned int)__bfloat16_as_ushort(__float2bfloat16(s1)) |
              ((unsigned int)__bfloat16_as_ushort(__float2bfloat16(c1)) << 16);
      bw[2] = (unsigned int)__bfloat16_as_ushort(__float2bfloat16(s2)) |
              ((unsigned int)__bfloat16_as_ushort(__float2bfloat16(c2)) << 16);
      bw[3] = (unsigned int)__bfloat16_as_ushort(__float2bfloat16(s3)) |
              ((unsigned int)__bfloat16_as_ushort(__float2bfloat16(c3)) << 16);
    }
    UA ub;
    ub.u = make_uint4(bw[0], bw[1], bw[2], bw[3]);
    bf16x8 bfrag = ub.v;

    // A fragments: row m = mt*16+lo, uint index m*256 + ks*16 + hi*4
    const int abase = ks * 16 + hi * 4;
    UA ua0, ua1, ua2, ua3;
    ua0.u = *(const uint4*)(A + (0 * 16 + lo) * (KDIM / 2) + abase);
    ua1.u = *(const uint4*)(A + (1 * 16 + lo) * (KDIM / 2) + abase);
    ua2.u = *(const uint4*)(A + (2 * 16 + lo) * (KDIM / 2) + abase);
    ua3.u = *(const uint4*)(A + (3 * 16 + lo) * (KDIM / 2) + abase);

    acc0 = __builtin_amdgcn_mfma_f32_16x16x32_bf16(ua0.v, bfrag, acc0, 0, 0, 0);
    acc1 = __builtin_amdgcn_mfma_f32_16x16x32_bf16(ua1.v, bfrag, acc1, 0, 0, 0);
    acc2 = __builtin_amdgcn_mfma_f32_16x16x32_bf16(ua2.v, bfrag, acc2, 0, 0, 0);
    acc3 = __builtin_amdgcn_mfma_f32_16x16x32_bf16(ua3.v, bfrag, acc3, 0, 0, 0);

    pe = pe_next;
  }

  // C/D layout (verified m89): col = lane&15, row = (lane>>4)*4 + reg
#pragma unroll
  for (int r = 0; r < 4; ++r) {
    out[(long)(0 * 16 + hi * 4 + r) * NE + e] = acc0[r];
    out[(long)(1 * 16 + hi * 4 + r) * NE + e] = acc1[r];
    out[(long)(2 * 16 + hi * 4 + r) * NE + e] = acc2[r];
    out[(long)(3 * 16 + hi * 4 + r) * NE + e] = acc3[r];
  }
}

extern "C" void kernel_launch(void* const* d_in, const int* in_sizes, int n_in,
                              void* d_out, int out_size, void* d_ws,
                              size_t ws_size, hipStream_t stream) {
  const int* triples = (const int*)d_in[0];     // int32 (JAX demotes int64)
  const float* ent = (const float*)d_in[1];     // [NE][256]
  const float* rel = (const float*)d_in[2];     // [NR][256]
  float* out = (float*)d_out;

  const int n_ent = in_sizes[1];
  const int n_rel = in_sizes[2];
  const int NE = n_ent / EMB_D;  // 50000

  unsigned int* ws = (unsigned int*)d_ws;     // ws[0]=max_ent bits, ws[1]=max_rel bits
  unsigned int* A = (unsigned int*)((char*)d_ws + 256);  // 64KB bf16 A matrix

  init_ws_kernel<<<1, 1, 0, stream>>>(ws);
  absmax_kernel<<<2048, 256, 0, stream>>>(ent, rel, n_ent, n_rel, ws);
  build_A_kernel<<<BATCH, EMB_D, 0, stream>>>(triples, ent, rel, ws, A);
  score_kernel<<<NE / 16, 64, 0, stream>>>(ent, A, ws, out, NE);
}

// Round 2
// 57.184 us; speedup vs baseline: 2.6773x; 2.6773x over previous
//
#include <hip/hip_runtime.h>
#include <hip/hip_bf16.h>

// pRotatE scoring: out[b,e] = -sum_d sin(ph[b,d] - pe[e,d])
// Rewritten via sin(x-y)=sinx cosy - cosx siny as a bf16 MFMA GEMM:
//   out = A(64x512) * B(512x50000),  A[b][2d]=cos(ph), A[b][2d+1]=-sin(ph)
//                                    B[2d][e]=sin(pe), B[2d+1][e]=cos(pe)
// v_sin_f32/v_cos_f32 take REVOLUTIONS: rev = x * (0.5/max), |rev|<=1.
//
// R1 lessons: same-address atomicMax serialized at ~14ns/op = 112us ->
// replaced with two-stage tree reduction (plain stores). Score kernel was
// latency-bound (unpipelined L2 A-loads feeding MFMA) -> all pe loads
// hoisted, A-fragments prefetched depth-3.

typedef __bf16 bf16x8 __attribute__((ext_vector_type(8)));
typedef float f32x4 __attribute__((ext_vector_type(4)));

#define EMB_D 256   // emb_dim
#define KDIM 512    // 2 * EMB_D
#define BATCH 64
#define NB_HALF 1024  // stage-1 blocks per tensor

// ws layout (bytes): [0,8) = {max_ent, max_rel} floats
//                    [64, 64+8192) = stage-1 partials (2048 floats)
//                    [16384, 16384+65536) = A matrix (bf16 64x512)

__global__ __launch_bounds__(256) void absmax_stage1(
    const float* __restrict__ ent, const float* __restrict__ rel,
    int n_ent, int n_rel, float* __restrict__ partial) {
  const bool is_ent = (int)blockIdx.x < NB_HALF;
  const float* __restrict__ src = is_ent ? ent : rel;
  const int n = is_ent ? n_ent : n_rel;
  const int bid = is_ent ? (int)blockIdx.x : (int)blockIdx.x - NB_HALF;
  const int nvec = n >> 2;
  const float4* __restrict__ v = (const float4*)src;
  float m = 0.0f;
  for (int i = bid * 256 + threadIdx.x; i < nvec; i += NB_HALF * 256) {
    float4 x = v[i];
    m = fmaxf(m, fmaxf(fmaxf(fabsf(x.x), fabsf(x.y)),
                       fmaxf(fabsf(x.z), fabsf(x.w))));
  }
#pragma unroll
  for (int off = 32; off > 0; off >>= 1)
    m = fmaxf(m, __shfl_down(m, off, 64));
  __shared__ float sm[4];
  if ((threadIdx.x & 63) == 0) sm[threadIdx.x >> 6] = m;
  __syncthreads();
  if (threadIdx.x == 0)
    partial[blockIdx.x] = fmaxf(fmaxf(sm[0], sm[1]), fmaxf(sm[2], sm[3]));
}

__global__ __launch_bounds__(256) void absmax_stage2(
    const float* __restrict__ partial, float* __restrict__ wsf) {
  const int t = threadIdx.x;
  float me = 0.0f, mr = 0.0f;
#pragma unroll
  for (int i = 0; i < NB_HALF / 256; ++i) {
    me = fmaxf(me, partial[i * 256 + t]);
    mr = fmaxf(mr, partial[NB_HALF + i * 256 + t]);
  }
#pragma unroll
  for (int off = 32; off > 0; off >>= 1) {
    me = fmaxf(me, __shfl_down(me, off, 64));
    mr = fmaxf(mr, __shfl_down(mr, off, 64));
  }
  __shared__ float sme[4], smr[4];
  if ((t & 63) == 0) {
    sme[t >> 6] = me;
    smr[t >> 6] = mr;
  }
  __syncthreads();
  if (t == 0) {
    wsf[0] = fmaxf(fmaxf(sme[0], sme[1]), fmaxf(sme[2], sme[3]));
    wsf[1] = fmaxf(fmaxf(smr[0], smr[1]), fmaxf(smr[2], smr[3]));
  }
}

// A[64][512] bf16, stored as uint pairs: uint index b*256+d holds
// (low) A[b][2d] = cos(ph), (high) A[b][2d+1] = -sin(ph)
__global__ __launch_bounds__(256) void build_A_kernel(
    const int* __restrict__ triples, const float* __restrict__ ent,
    const float* __restrict__ rel, const float* __restrict__ wsf,
    unsigned int* __restrict__ A) {
  const int b = blockIdx.x;    // 0..63
  const int d = threadIdx.x;   // 0..255
  const float max_e = wsf[0];
  const float max_r = wsf[1];
  const int h = triples[b * 3 + 0];
  const int r = triples[b * 3 + 1];
  const float rev = ent[h * EMB_D + d] * (0.5f / max_e) +
                    rel[r * EMB_D + d] * (0.5f / max_r);
  const float s = __builtin_amdgcn_sinf(rev);
  const float c = __builtin_amdgcn_cosf(rev);
  const unsigned int cb = (unsigned int)__bfloat16_as_ushort(__float2bfloat16(c));
  const unsigned int nsb = (unsigned int)__bfloat16_as_ushort(__float2bfloat16(-s));
  A[b * (KDIM / 2) + d] = cb | (nsb << 16);
}

// One wave per block; wave computes C[64 b][16 e], K=512 in 16 k-steps of
// mfma_f32_16x16x32_bf16 x 4 m-tiles. All 16 pe float4 loads hoisted to
// prologue; A fragments prefetched with depth-3 rotation.
__global__ __launch_bounds__(64, 3) void score_kernel(
    const float* __restrict__ ent, const unsigned int* __restrict__ A,
    const float* __restrict__ wsf, float* __restrict__ out, int NE) {
  const int lane = threadIdx.x;
  const int lo = lane & 15;
  const int hi = lane >> 4;
  const int e = blockIdx.x * 16 + lo;
  const float scale = 0.5f / wsf[0];

  f32x4 acc[4];
#pragma unroll
  for (int mt = 0; mt < 4; ++mt)
#pragma unroll
    for (int r = 0; r < 4; ++r) acc[mt][r] = 0.0f;

  const float4* __restrict__ erow = (const float4*)(ent + (long)e * EMB_D);
  const uint4* __restrict__ A4 = (const uint4*)A;

  union UA {
    uint4 u;
    bf16x8 v;
  };

  // hoist all ent loads (16 float4 = 64 VGPRs)
  float4 pe[16];
#pragma unroll
  for (int ks = 0; ks < 16; ++ks) pe[ks] = erow[ks * 4 + hi];

  // A fragment rotating prefetch, depth 3
  uint4 a[3][4];
#pragma unroll
  for (int p = 0; p < 2; ++p)
#pragma unroll
    for (int mt = 0; mt < 4; ++mt)
      a[p][mt] = A4[(mt * 16 + lo) * 64 + p * 4 + hi];

#pragma unroll
  for (int ks = 0; ks < 16; ++ks) {
    if (ks + 2 < 16) {
#pragma unroll
      for (int mt = 0; mt < 4; ++mt)
        a[(ks + 2) % 3][mt] = A4[(mt * 16 + lo) * 64 + (ks + 2) * 4 + hi];
    }

    // build B fragment: elem 2t = sin(pe[t]), 2t+1 = cos(pe[t])
    const float f0 = pe[ks].x * scale, f1 = pe[ks].y * scale,
                f2 = pe[ks].z * scale, f3 = pe[ks].w * scale;
    const float s0 = __builtin_amdgcn_sinf(f0), c0 = __builtin_amdgcn_cosf(f0);
    const float s1 = __builtin_amdgcn_sinf(f1), c1 = __builtin_amdgcn_cosf(f1);
    const float s2 = __builtin_amdgcn_sinf(f2), c2 = __builtin_amdgcn_cosf(f2);
    const float s3 = __builtin_amdgcn_sinf(f3), c3 = __builtin_amdgcn_cosf(f3);
    UA ub;
    ub.u.x = (unsigned int)__bfloat16_as_ushort(__float2bfloat16(s0)) |
             ((unsigned int)__bfloat16_as_ushort(__float2bfloat16(c0)) << 16);
    ub.u.y = (unsigned int)__bfloat16_as_ushort(__float2bfloat16(s1)) |
             ((unsigned int)__bfloat16_as_ushort(__float2bfloat16(c1)) << 16);
    ub.u.z = (unsigned int)__bfloat16_as_ushort(__float2bfloat16(s2)) |
             ((unsigned int)__bfloat16_as_ushort(__float2bfloat16(c2)) << 16);
    ub.u.w = (unsigned int)__bfloat16_as_ushort(__float2bfloat16(s3)) |
             ((unsigned int)__bfloat16_as_ushort(__float2bfloat16(c3)) << 16);

#pragma unroll
    for (int mt = 0; mt < 4; ++mt) {
      UA ua;
      ua.u = a[ks % 3][mt];
      acc[mt] = __builtin_amdgcn_mfma_f32_16x16x32_bf16(ua.v, ub.v, acc[mt], 0, 0, 0);
    }
  }

  // C/D layout (verified m89): col = lane&15, row = (lane>>4)*4 + reg
#pragma unroll
  for (int mt = 0; mt < 4; ++mt)
#pragma unroll
    for (int r = 0; r < 4; ++r)
      out[(long)(mt * 16 + hi * 4 + r) * NE + e] = acc[mt][r];
}

extern "C" void kernel_launch(void* const* d_in, const int* in_sizes, int n_in,
                              void* d_out, int out_size, void* d_ws,
                              size_t ws_size, hipStream_t stream) {
  const int* triples = (const int*)d_in[0];
  const float* ent = (const float*)d_in[1];   // [NE][256]
  const float* rel = (const float*)d_in[2];   // [NR][256]
  float* out = (float*)d_out;

  const int n_ent = in_sizes[1];
  const int n_rel = in_sizes[2];
  const int NE = n_ent / EMB_D;  // 50000

  float* wsf = (float*)d_ws;
  float* partial = (float*)((char*)d_ws + 64);
  unsigned int* A = (unsigned int*)((char*)d_ws + 16384);

  absmax_stage1<<<2 * NB_HALF, 256, 0, stream>>>(ent, rel, n_ent, n_rel, partial);
  absmax_stage2<<<1, 256, 0, stream>>>(partial, wsf);
  build_A_kernel<<<BATCH, EMB_D, 0, stream>>>(triples, ent, rel, wsf, A);
  score_kernel<<<NE / 16, 64, 0, stream>>>(ent, A, wsf, out, NE);
}

// Round 3
// 56.236 us; speedup vs baseline: 2.7224x; 1.0169x over previous
//
#include <hip/hip_runtime.h>
#include <hip/hip_bf16.h>

// pRotatE scoring: out[b,e] = -sum_d sin(ph[b,d] - pe[e,d])
// Rewritten via sin(x-y)=sinx cosy - cosx siny as a bf16 MFMA GEMM:
//   out = A(64x512) * B(512x50000),  A[b][2d]=cos(ph), A[b][2d+1]=-sin(ph)
//                                    B[2d][e]=sin(pe), B[2d+1][e]=cos(pe)
// v_sin_f32/v_cos_f32 take REVOLUTIONS: rev = x * (0.5/max), |rev|<=1.
//
// R1: same-address atomicMax serialized (112us) -> two-stage tree reduction.
// R2: stage2 launch folded into build_A (redundant per-block partial reduce);
//     score_kernel had __launch_bounds__(64,3) capping VGPR<=168 while the
//     hoisted pe[16]+a[3][4] wanted ~190 -> likely scratch spills. Now:
//     quarter-buffered pe (32 regs) + depth-4 A prefetch (64 regs), no cap.

typedef __bf16 bf16x8 __attribute__((ext_vector_type(8)));
typedef float f32x4 __attribute__((ext_vector_type(4)));

#define EMB_D 256   // emb_dim
#define KDIM 512    // 2 * EMB_D
#define BATCH 64
#define NB_HALF 1024  // stage-1 blocks per tensor

// ws layout (bytes): [0,8) = {max_ent, max_rel} floats
//                    [64, 64+8192) = stage-1 partials (2048 floats)
//                    [16384, 16384+65536) = A matrix (bf16 64x512)

__global__ __launch_bounds__(256) void absmax_stage1(
    const float* __restrict__ ent, const float* __restrict__ rel,
    int n_ent, int n_rel, float* __restrict__ partial) {
  const bool is_ent = (int)blockIdx.x < NB_HALF;
  const float* __restrict__ src = is_ent ? ent : rel;
  const int n = is_ent ? n_ent : n_rel;
  const int bid = is_ent ? (int)blockIdx.x : (int)blockIdx.x - NB_HALF;
  const int nvec = n >> 2;
  const float4* __restrict__ v = (const float4*)src;
  float m = 0.0f;
#pragma unroll 2
  for (int i = bid * 256 + threadIdx.x; i < nvec; i += NB_HALF * 256) {
    float4 x = v[i];
    m = fmaxf(m, fmaxf(fmaxf(fabsf(x.x), fabsf(x.y)),
                       fmaxf(fabsf(x.z), fabsf(x.w))));
  }
#pragma unroll
  for (int off = 32; off > 0; off >>= 1)
    m = fmaxf(m, __shfl_down(m, off, 64));
  __shared__ float sm[4];
  if ((threadIdx.x & 63) == 0) sm[threadIdx.x >> 6] = m;
  __syncthreads();
  if (threadIdx.x == 0)
    partial[blockIdx.x] = fmaxf(fmaxf(sm[0], sm[1]), fmaxf(sm[2], sm[3]));
}

// Each block: (a) redundantly reduces the 2048 stage-1 partials to the two
// global maxes (saves a separate stage-2 launch), (b) builds its batch row of
// A. Block 0 also publishes the maxes to wsf for score_kernel.
__global__ __launch_bounds__(256) void build_A_kernel(
    const int* __restrict__ triples, const float* __restrict__ ent,
    const float* __restrict__ rel, const float* __restrict__ partial,
    float* __restrict__ wsf, unsigned int* __restrict__ A) {
  const int t = threadIdx.x;
  float me = 0.0f, mr = 0.0f;
#pragma unroll
  for (int i = 0; i < NB_HALF / 256; ++i) {
    me = fmaxf(me, partial[i * 256 + t]);
    mr = fmaxf(mr, partial[NB_HALF + i * 256 + t]);
  }
#pragma unroll
  for (int off = 32; off > 0; off >>= 1) {
    me = fmaxf(me, __shfl_down(me, off, 64));
    mr = fmaxf(mr, __shfl_down(mr, off, 64));
  }
  __shared__ float sme[4], smr[4];
  if ((t & 63) == 0) {
    sme[t >> 6] = me;
    smr[t >> 6] = mr;
  }
  __syncthreads();
  const float max_e = fmaxf(fmaxf(sme[0], sme[1]), fmaxf(sme[2], sme[3]));
  const float max_r = fmaxf(fmaxf(smr[0], smr[1]), fmaxf(smr[2], smr[3]));
  const int b = blockIdx.x;  // 0..63
  if (b == 0 && t == 0) {
    wsf[0] = max_e;
    wsf[1] = max_r;
  }
  const int h = triples[b * 3 + 0];
  const int r = triples[b * 3 + 1];
  const float rev = ent[h * EMB_D + t] * (0.5f / max_e) +
                    rel[r * EMB_D + t] * (0.5f / max_r);
  const float s = __builtin_amdgcn_sinf(rev);
  const float c = __builtin_amdgcn_cosf(rev);
  const unsigned int cb = (unsigned int)__bfloat16_as_ushort(__float2bfloat16(c));
  const unsigned int nsb = (unsigned int)__bfloat16_as_ushort(__float2bfloat16(-s));
  A[b * (KDIM / 2) + t] = cb | (nsb << 16);
}

// One wave per block; wave computes C[64 b][16 e], K=512 in 16 k-steps of
// mfma_f32_16x16x32_bf16 x 4 m-tiles. pe held in two rotating quarter-buffers
// (4 float4 each, next quarter prefetched at quarter start); A fragments in a
// depth-4 rotating buffer (prefetch 3 k-steps ahead ~ L2 latency). All
// indices static under full unroll -> everything stays in registers.
__global__ __launch_bounds__(64) void score_kernel(
    const float* __restrict__ ent, const unsigned int* __restrict__ A,
    const float* __restrict__ wsf, float* __restrict__ out, int NE) {
  const int lane = threadIdx.x;
  const int lo = lane & 15;
  const int hi = lane >> 4;
  const int e = blockIdx.x * 16 + lo;
  const float scale = 0.5f / wsf[0];

  f32x4 acc[4];
#pragma unroll
  for (int mt = 0; mt < 4; ++mt)
#pragma unroll
    for (int r = 0; r < 4; ++r) acc[mt][r] = 0.0f;

  const float4* __restrict__ erow = (const float4*)(ent + (long)e * EMB_D);
  const uint4* __restrict__ A4 = (const uint4*)A;

  union UA {
    uint4 u;
    bf16x8 v;
  };

  float4 pq[2][4];   // two quarter-buffers of pe
  uint4 a[4][4];     // rotating A-fragment prefetch, depth 4

#pragma unroll
  for (int j = 0; j < 4; ++j) pq[0][j] = erow[j * 4 + hi];
#pragma unroll
  for (int p = 0; p < 3; ++p)
#pragma unroll
    for (int mt = 0; mt < 4; ++mt)
      a[p][mt] = A4[(mt * 16 + lo) * 64 + p * 4 + hi];

#pragma unroll
  for (int ks = 0; ks < 16; ++ks) {
    const int qsel = (ks >> 2) & 1;
    if ((ks & 3) == 0 && ks + 4 < 16) {
#pragma unroll
      for (int j = 0; j < 4; ++j)
        pq[qsel ^ 1][j] = erow[(ks + 4 + j) * 4 + hi];
    }
    if (ks + 3 < 16) {
#pragma unroll
      for (int mt = 0; mt < 4; ++mt)
        a[(ks + 3) & 3][mt] = A4[(mt * 16 + lo) * 64 + (ks + 3) * 4 + hi];
    }

    const float4 pe = pq[qsel][ks & 3];
    const float f0 = pe.x * scale, f1 = pe.y * scale, f2 = pe.z * scale,
                f3 = pe.w * scale;
    const float s0 = __builtin_amdgcn_sinf(f0), c0 = __builtin_amdgcn_cosf(f0);
    const float s1 = __builtin_amdgcn_sinf(f1), c1 = __builtin_amdgcn_cosf(f1);
    const float s2 = __builtin_amdgcn_sinf(f2), c2 = __builtin_amdgcn_cosf(f2);
    const float s3 = __builtin_amdgcn_sinf(f3), c3 = __builtin_amdgcn_cosf(f3);
    UA ub;
    ub.u.x = (unsigned int)__bfloat16_as_ushort(__float2bfloat16(s0)) |
             ((unsigned int)__bfloat16_as_ushort(__float2bfloat16(c0)) << 16);
    ub.u.y = (unsigned int)__bfloat16_as_ushort(__float2bfloat16(s1)) |
             ((unsigned int)__bfloat16_as_ushort(__float2bfloat16(c1)) << 16);
    ub.u.z = (unsigned int)__bfloat16_as_ushort(__float2bfloat16(s2)) |
             ((unsigned int)__bfloat16_as_ushort(__float2bfloat16(c2)) << 16);
    ub.u.w = (unsigned int)__bfloat16_as_ushort(__float2bfloat16(s3)) |
             ((unsigned int)__bfloat16_as_ushort(__float2bfloat16(c3)) << 16);

#pragma unroll
    for (int mt = 0; mt < 4; ++mt) {
      UA ua;
      ua.u = a[ks & 3][mt];
      acc[mt] = __builtin_amdgcn_mfma_f32_16x16x32_bf16(ua.v, ub.v, acc[mt], 0, 0, 0);
    }
  }

  // C/D layout (verified m89): col = lane&15, row = (lane>>4)*4 + reg
#pragma unroll
  for (int mt = 0; mt < 4; ++mt)
#pragma unroll
    for (int r = 0; r < 4; ++r)
      out[(long)(mt * 16 + hi * 4 + r) * NE + e] = acc[mt][r];
}

extern "C" void kernel_launch(void* const* d_in, const int* in_sizes, int n_in,
                              void* d_out, int out_size, void* d_ws,
                              size_t ws_size, hipStream_t stream) {
  const int* triples = (const int*)d_in[0];
  const float* ent = (const float*)d_in[1];   // [NE][256]
  const float* rel = (const float*)d_in[2];   // [NR][256]
  float* out = (float*)d_out;

  const int n_ent = in_sizes[1];
  const int n_rel = in_sizes[2];
  const int NE = n_ent / EMB_D;  // 50000

  float* wsf = (float*)d_ws;
  float* partial = (float*)((char*)d_ws + 64);
  unsigned int* A = (unsigned int*)((char*)d_ws + 16384);

  absmax_stage1<<<2 * NB_HALF, 256, 0, stream>>>(ent, rel, n_ent, n_rel, partial);
  build_A_kernel<<<BATCH, EMB_D, 0, stream>>>(triples, ent, rel, partial, wsf, A);
  score_kernel<<<NE / 16, 64, 0, stream>>>(ent, A, wsf, out, NE);
}